// Round 7
// baseline (758.609 us; speedup 1.0000x reference)
//
#include <hip/hip_runtime.h>
#include <hip/hip_bf16.h>
#include <math.h>

#define NB 2
#define LL 2048
#define DD 768
#define DI 1536
#define DS 16
#define MM (NB*LL)   // 4096
#define TCH 128      // scan chunk length
#define NCH 16       // 2048 / TCH

typedef __hip_bfloat16 bf16;
typedef __attribute__((ext_vector_type(8))) __bf16 bf16x8;
typedef __attribute__((ext_vector_type(4))) float f32x4;

__device__ __forceinline__ float b2f(bf16 v){ return __bfloat162float(v); }
__device__ __forceinline__ bf16 f2b(float v){ return __float2bfloat16(v); }

__device__ __forceinline__ void un2(unsigned u, float& lo, float& hi){
  union {unsigned i; float f;} a, b;
  a.i = u << 16; b.i = u & 0xffff0000u;
  lo = a.f; hi = b.f;
}

__device__ __forceinline__ void async_cp16(const bf16* g, __bf16* l) {
  __builtin_amdgcn_global_load_lds((const __attribute__((address_space(1))) void*)g,
                                   (__attribute__((address_space(3))) void*)l, 16, 0, 0);
}

#define ACT_NONE 0
#define ACT_SOFTPLUS 1
#define ACT_GELU 2

__device__ __forceinline__ float apply_act(float v, int act) {
  if (act == ACT_SOFTPLUS) {
    v = (v > 15.f) ? v : log1pf(__expf(v));
  } else if (act == ACT_GELU) {
    float u = 0.7978845608028654f * (v + 0.044715f*v*v*v);
    v = 0.5f * v * (1.f + tanhf(u));
  }
  return v;
}

// ---------------- 128x128 tile, BK=64, XOR-swizzled LDS ----------------
// C[M,N] = A[M,K] @ B[N,K]^T (+bias) ->act. K % 64 == 0.
// LDS[row][g] holds global col-group (g ^ (row&7)); readers XOR back.
__global__ void gemm_kernel(const bf16* __restrict__ A, int lda,
                            const bf16* __restrict__ B, int ldb,
                            void* __restrict__ C, int ldc,
                            int N, int K,
                            const float* __restrict__ bias,
                            const float* __restrict__ addp, int ldadd,
                            int act, int f32out)
{
  __shared__ __bf16 As[128*64];   // 16 KB
  __shared__ __bf16 Bs[128*64];   // 16 KB
  const int tid  = threadIdx.x;
  const int lane = tid & 63, wave = tid >> 6;
  const int m0 = blockIdx.x * 128, n0 = blockIdx.y * 128;
  const int wm = wave & 1, wn = wave >> 1;

  // staging: 8 lanes per row; swizzled global column group
  const int srow = wave*32 + (lane >> 3);
  const int gsw  = (lane & 7) ^ ((lane >> 3) & 7);
  const int scol = gsw * 8;
  const bf16* Ag[4]; const bf16* Bg[4];
  __bf16 *AsW[4], *BsW[4];
  #pragma unroll
  for (int i = 0; i < 4; i++) {
    int ar = m0 + srow + i*8;
    Ag[i] = A + (size_t)ar * lda + scol;
    int br = n0 + srow + i*8; if (br > N-1) br = N-1;
    Bg[i] = B + (size_t)br * ldb + scol;
    AsW[i] = &As[(wave*32 + i*8)*64];
    BsW[i] = &Bs[(wave*32 + i*8)*64];
  }

  f32x4 acc[4][4] = {};
  const int arow = wm*64 + (lane & 15);
  const int brow = wn*64 + (lane & 15);
  const int rx = lane & 7;        // row&7 for frag reads
  const int gq = lane >> 4;       // quarter index

  for (int kb = 0; kb < K; kb += 64) {
    __syncthreads();
    #pragma unroll
    for (int i = 0; i < 4; i++) {
      async_cp16(Ag[i] + kb, AsW[i]);
      async_cp16(Bg[i] + kb, BsW[i]);
    }
    __syncthreads();
    #pragma unroll
    for (int h = 0; h < 2; h++) {
      const int kk = ((h*4 + gq) ^ rx) * 8;   // swizzled LDS column
      bf16x8 af[4], bfr[4];
      #pragma unroll
      for (int i = 0; i < 4; i++) af[i]  = *(const bf16x8*)&As[(arow + i*16)*64 + kk];
      #pragma unroll
      for (int j = 0; j < 4; j++) bfr[j] = *(const bf16x8*)&Bs[(brow + j*16)*64 + kk];
      #pragma unroll
      for (int i = 0; i < 4; i++)
        #pragma unroll
        for (int j = 0; j < 4; j++)
          acc[i][j] = __builtin_amdgcn_mfma_f32_16x16x32_bf16(af[i], bfr[j], acc[i][j], 0, 0, 0);
    }
  }

  bf16*  Cb = (bf16*)C;
  float* Cf = (float*)C;
  #pragma unroll
  for (int i = 0; i < 4; i++) {
    int rbase = m0 + wm*64 + i*16 + (lane >> 4)*4;
    #pragma unroll
    for (int j = 0; j < 4; j++) {
      int col = n0 + wn*64 + j*16 + (lane & 15);
      if (col >= N) continue;
      float bv = bias ? bias[col] : 0.f;
      #pragma unroll
      for (int r = 0; r < 4; r++) {
        int row = rbase + r;
        float v = apply_act(acc[i][j][r] + bv, act);
        if (addp) v += addp[(size_t)row * ldadd + col];
        if (f32out) Cf[(size_t)row * ldc + col] = v;
        else        Cb[(size_t)row * ldc + col] = f2b(v);
      }
    }
  }
}

// ---------------- 64x64 tile, BK=64, swizzled, z-strided ----------------
__global__ void gemm64_kernel(const bf16* __restrict__ A, int lda, size_t sA,
                              const bf16* __restrict__ B, int ldb, size_t sB,
                              void* __restrict__ C, int ldc, size_t sC,
                              int N, int K,
                              const float* __restrict__ bias0,
                              const float* __restrict__ bias1, int biasBase,
                              const float* __restrict__ addp, int ldadd,
                              int act, int f32out)
{
  __shared__ __bf16 As[64*64];    // 8 KB
  __shared__ __bf16 Bs[64*64];    // 8 KB
  const int tid  = threadIdx.x;
  const int lane = tid & 63, wave = tid >> 6;
  const int z = blockIdx.z;
  A += (size_t)z * sA;
  B += (size_t)z * sB;
  const float* bias = ((biasBase + z) ? bias1 : bias0);
  const int m0 = blockIdx.x * 64, n0 = blockIdx.y * 64;
  const int wm = wave & 1, wn = wave >> 1;

  const int srow = wave*16 + (lane >> 3);
  const int gsw  = (lane & 7) ^ ((lane >> 3) & 7);
  const int scol = gsw * 8;
  const bf16* Ag[2]; const bf16* Bg[2];
  __bf16 *AsW[2], *BsW[2];
  #pragma unroll
  for (int i = 0; i < 2; i++) {
    int ar = m0 + srow + i*8;
    Ag[i] = A + (size_t)ar * lda + scol;
    int br = n0 + srow + i*8; if (br > N-1) br = N-1;
    Bg[i] = B + (size_t)br * ldb + scol;
    AsW[i] = &As[(wave*16 + i*8)*64];
    BsW[i] = &Bs[(wave*16 + i*8)*64];
  }

  f32x4 acc[2][2] = {};
  const int arow = wm*32 + (lane & 15);
  const int brow = wn*32 + (lane & 15);
  const int rx = lane & 7;
  const int gq = lane >> 4;

  for (int kb = 0; kb < K; kb += 64) {
    __syncthreads();
    #pragma unroll
    for (int i = 0; i < 2; i++) {
      async_cp16(Ag[i] + kb, AsW[i]);
      async_cp16(Bg[i] + kb, BsW[i]);
    }
    __syncthreads();
    #pragma unroll
    for (int h = 0; h < 2; h++) {
      const int kk = ((h*4 + gq) ^ rx) * 8;
      bf16x8 af[2], bfr[2];
      #pragma unroll
      for (int i = 0; i < 2; i++) af[i]  = *(const bf16x8*)&As[(arow + i*16)*64 + kk];
      #pragma unroll
      for (int j = 0; j < 2; j++) bfr[j] = *(const bf16x8*)&Bs[(brow + j*16)*64 + kk];
      #pragma unroll
      for (int i = 0; i < 2; i++)
        #pragma unroll
        for (int j = 0; j < 2; j++)
          acc[i][j] = __builtin_amdgcn_mfma_f32_16x16x32_bf16(af[i], bfr[j], acc[i][j], 0, 0, 0);
    }
  }

  bf16*  Cb = (bf16*)C + z*sC;
  float* Cf = (float*)C + z*sC;
  #pragma unroll
  for (int i = 0; i < 2; i++) {
    int rbase = m0 + wm*32 + i*16 + (lane >> 4)*4;
    #pragma unroll
    for (int j = 0; j < 2; j++) {
      int col = n0 + wn*32 + j*16 + (lane & 15);
      if (col >= N) continue;
      float bv = bias ? bias[col] : 0.f;
      #pragma unroll
      for (int r = 0; r < 4; r++) {
        int row = rbase + r;
        float v = apply_act(acc[i][j][r] + bv, act);
        if (addp) v += addp[(size_t)row * ldadd + col];
        if (f32out) Cf[(size_t)row * ldc + col] = v;
        else        Cb[(size_t)row * ldc + col] = f2b(v);
      }
    }
  }
}

// ---------------- LayerNorm over D=768; fp32 in, bf16 out ----------------
__global__ void ln_kernel(const float* __restrict__ x, const float* __restrict__ g,
                          const float* __restrict__ b, bf16* __restrict__ out)
{
  const int row = blockIdx.x;
  const int tid = threadIdx.x;
  const float* xr = x + (size_t)row * DD;
  float v[3], s = 0.f, s2 = 0.f;
  #pragma unroll
  for (int i = 0; i < 3; i++) {
    float f = xr[tid + i*256];
    v[i] = f; s += f; s2 += f*f;
  }
  #pragma unroll
  for (int o = 32; o > 0; o >>= 1) { s += __shfl_down(s, o, 64); s2 += __shfl_down(s2, o, 64); }
  __shared__ float ps[4], ps2[4];
  int wave = tid >> 6;
  if ((tid & 63) == 0) { ps[wave] = s; ps2[wave] = s2; }
  __syncthreads();
  s = ps[0]+ps[1]+ps[2]+ps[3]; s2 = ps2[0]+ps2[1]+ps2[2]+ps2[3];
  float mu = s * (1.f/DD);
  float var = s2 * (1.f/DD) - mu*mu;
  float rs = rsqrtf(var + 1e-5f);
  #pragma unroll
  for (int i = 0; i < 3; i++) {
    int c = tid + i*256;
    float o = (v[i] - mu) * rs * g[c] + b[c];
    out[(size_t)row * DD + c] = f2b(o);
  }
}

// ---------------- conv(K=4) + silu; dir0 causal, dir1 anti-causal --------
__global__ void conv_silu_kernel(const bf16* __restrict__ xz, int ldxz, int xzDirOff,
                                 const float* __restrict__ cw0, const float* __restrict__ cb0,
                                 const float* __restrict__ cw1, const float* __restrict__ cb1,
                                 bf16* __restrict__ xc, size_t sXc, int dirBase)
{
  int idx = blockIdx.x * 256 + threadIdx.x;
  int sIdx = (idx >= DI) ? 1 : 0;
  int d = idx - sIdx*DI;
  int dir = dirBase + sIdx;
  int row = blockIdx.y;
  int b = row >> 11, t = row & 2047;
  const float* cw = dir ? cw1 : cw0;
  const float* cb = dir ? cb1 : cb0;
  float acc = cb[d];
  float w0 = cw[d*4+0], w1 = cw[d*4+1], w2 = cw[d*4+2], w3 = cw[d*4+3];
  const bf16* base = xz + (size_t)(b*2048) * ldxz + sIdx*xzDirOff + d;
  if (dir == 0) {
    if (t >= 3) acc += b2f(base[(size_t)(t-3)*ldxz]) * w0;
    if (t >= 2) acc += b2f(base[(size_t)(t-2)*ldxz]) * w1;
    if (t >= 1) acc += b2f(base[(size_t)(t-1)*ldxz]) * w2;
    acc += b2f(base[(size_t)t*ldxz]) * w3;
  } else {
    if (t <= 2044) acc += b2f(base[(size_t)(t+3)*ldxz]) * w0;
    if (t <= 2045) acc += b2f(base[(size_t)(t+2)*ldxz]) * w1;
    if (t <= 2046) acc += b2f(base[(size_t)(t+1)*ldxz]) * w2;
    acc += b2f(base[(size_t)t*ldxz]) * w3;
  }
  float y = acc / (1.f + __expf(-acc));
  xc[sIdx*sXc + (size_t)row * DI + d] = f2b(y);
}

// ---------------- one-shot weight prep (all dirs + shared) ----------------
#define SZ_INW (2*DI*DD)
#define SZ_XP  (80*DI)
#define SZ_OUT (DD*DI)
#define SZ_DTW (DI*64)
#define SZ_AN  (DI*16)
#define SZ_MIX (2*DD*DD)
#define SZ_F1  (4*DD*DD)
__global__ void prep_all_kernel(const float* fi, const float* bi,
                                const float* fxp, const float* bxp,
                                const float* fo, const float* bo,
                                const float* fdt, const float* bdt,
                                const float* fa, const float* ba,
                                const float* mw, const float* f1, const float* f2,
                                bf16* w_in, bf16* w_xp2, bf16* w_out2, bf16* dtwp2,
                                float* An2, bf16* w_mix, bf16* w_f1, bf16* w_f2)
{
  int i = blockIdx.x * 256 + threadIdx.x;
  if (i < SZ_INW) { w_in[i] = f2b(fi[i]); return; }               i -= SZ_INW;
  if (i < SZ_INW) { w_in[SZ_INW + i] = f2b(bi[i]); return; }      i -= SZ_INW;
  if (i < SZ_XP)  { w_xp2[i] = f2b(fxp[i]); return; }             i -= SZ_XP;
  if (i < SZ_XP)  { w_xp2[SZ_XP + i] = f2b(bxp[i]); return; }     i -= SZ_XP;
  if (i < SZ_OUT) { w_out2[i] = f2b(fo[i]); return; }             i -= SZ_OUT;
  if (i < SZ_OUT) { w_out2[SZ_OUT + i] = f2b(bo[i]); return; }    i -= SZ_OUT;
  if (i < SZ_DTW) { int r=i>>6,c=i&63; dtwp2[i] = (c<48)?f2b(fdt[r*48+c]):f2b(0.f); return; } i -= SZ_DTW;
  if (i < SZ_DTW) { int r=i>>6,c=i&63; dtwp2[SZ_DTW+i] = (c<48)?f2b(bdt[r*48+c]):f2b(0.f); return; } i -= SZ_DTW;
  if (i < SZ_AN)  { int d=i>>4,s=i&15; An2[s*DI+d] = -__expf(fa[i]); return; } i -= SZ_AN;
  if (i < SZ_AN)  { int d=i>>4,s=i&15; An2[SZ_AN + s*DI+d] = -__expf(ba[i]); return; } i -= SZ_AN;
  if (i < SZ_MIX) { w_mix[i] = f2b(mw[i]); return; }              i -= SZ_MIX;
  if (i < SZ_F1)  { w_f1[i] = f2b(f1[i]); return; }               i -= SZ_F1;
  w_f2[i] = f2b(f2[i]);
}

// ---------------- chunked parallel scan (dir-aware) ----------------
// z decodes (sIdx, b): sIdx = z>>1, b = z&1; dir = dirBase + sIdx.
__global__ void scan_partial(const bf16* __restrict__ dt, size_t sDt,
                             const bf16* __restrict__ xc, size_t sXc,
                             const bf16* __restrict__ dbc, size_t sDbc,
                             const float* __restrict__ An, size_t sAn,
                             float* __restrict__ Pp, float* __restrict__ Sp,
                             int dirBase)
{
  const int tid = threadIdx.x;
  const int sIdx = blockIdx.z >> 1, b = blockIdx.z & 1;
  const int dir = dirBase + sIdx;
  const int c = blockIdx.y;
  const int d = blockIdx.x * 256 + tid;
  dt  += sIdx*sDt; xc += sIdx*sXc; dbc += sIdx*sDbc;
  const int rowbase = b*2048 + c*TCH;
  __shared__ unsigned bcs[TCH*16];
  for (int i = tid; i < TCH*16; i += 256) {
    int r = i >> 4, dw = i & 15;
    bcs[i] = ((const unsigned*)(dbc + (size_t)(rowbase + r)*96 + 48))[dw];
  }
  __syncthreads();
  float A[16], P[16], g[16];
  #pragma unroll
  for (int s = 0; s < 16; s++) { A[s] = An[sIdx*sAn + s*DI + d]; P[s] = 1.f; g[s] = 0.f; }
  for (int t = 0; t < TCH; t++) {
    const int ph = dir ? (TCH-1-t) : t;
    const int row = rowbase + ph;
    float dtv = b2f(dt[(size_t)row*DI + d]);
    float xv  = b2f(xc[(size_t)row*DI + d]);
    unsigned ub[8];
    *(uint4*)&ub[0] = *(const uint4*)&bcs[ph*16];
    *(uint4*)&ub[4] = *(const uint4*)&bcs[ph*16 + 4];
    float Bv[16];
    #pragma unroll
    for (int k = 0; k < 8; k++) un2(ub[k], Bv[2*k], Bv[2*k+1]);
    float u = dtv * xv;
    #pragma unroll
    for (int s = 0; s < 16; s++) {
      float dA = __expf(dtv * A[s]);
      P[s] *= dA;
      g[s] = dA * g[s] + u * Bv[s];
    }
  }
  size_t base = ((((size_t)sIdx*NB + b)*NCH + c)*DI + d) * 16;
  #pragma unroll
  for (int s = 0; s < 16; s++) { Pp[base+s] = P[s]; Sp[base+s] = g[s]; }
}

__global__ void scan_combine(const float* __restrict__ Pp, const float* __restrict__ Sp,
                             float* __restrict__ h0, int dirBase)
{
  const int j = blockIdx.x * 256 + threadIdx.x;
  const int b = blockIdx.y;
  const int sIdx = blockIdx.z;
  const int dir = dirBase + sIdx;
  float h = 0.f;
  for (int k = 0; k < NCH; k++) {
    int c = dir ? (NCH-1-k) : k;
    size_t idx = (((size_t)sIdx*NB + b)*NCH + c)*DI*16 + j;
    h0[idx] = h;
    h = Pp[idx]*h + Sp[idx];
  }
}

__global__ void scan_final(const bf16* __restrict__ dt, size_t sDt,
                           const bf16* __restrict__ xc, size_t sXc,
                           const bf16* __restrict__ dbc, size_t sDbc,
                           const bf16* __restrict__ xz, int ldxz, int xzDirOff,
                           const float* __restrict__ An, size_t sAn,
                           const float* __restrict__ Dp0, const float* __restrict__ Dp1,
                           const float* __restrict__ h0,
                           bf16* __restrict__ yout, size_t sY, int dirBase)
{
  const int tid = threadIdx.x;
  const int sIdx = blockIdx.z >> 1, b = blockIdx.z & 1;
  const int dir = dirBase + sIdx;
  const int c = blockIdx.y;
  const int d = blockIdx.x * 256 + tid;
  dt += sIdx*sDt; xc += sIdx*sXc; dbc += sIdx*sDbc; yout += sIdx*sY;
  const float* Dp = dir ? Dp1 : Dp0;
  const int rowbase = b*2048 + c*TCH;
  __shared__ unsigned bcs[TCH*16];
  for (int i = tid; i < TCH*16; i += 256) {
    int r = i >> 4, dw = i & 15;
    bcs[i] = ((const unsigned*)(dbc + (size_t)(rowbase + r)*96 + 48))[dw];
  }
  __syncthreads();
  float A[16], h[16];
  size_t hbase = ((((size_t)sIdx*NB + b)*NCH + c)*DI + d) * 16;
  #pragma unroll
  for (int s = 0; s < 16; s++) { A[s] = An[sIdx*sAn + s*DI + d]; h[s] = h0[hbase+s]; }
  const float Dd = Dp[d];
  for (int t = 0; t < TCH; t++) {
    const int ph = dir ? (TCH-1-t) : t;
    const int row = rowbase + ph;
    float dtv = b2f(dt[(size_t)row*DI + d]);
    float xv  = b2f(xc[(size_t)row*DI + d]);
    unsigned ub[8], uc[8];
    *(uint4*)&ub[0] = *(const uint4*)&bcs[ph*16];
    *(uint4*)&ub[4] = *(const uint4*)&bcs[ph*16 + 4];
    *(uint4*)&uc[0] = *(const uint4*)&bcs[ph*16 + 8];
    *(uint4*)&uc[4] = *(const uint4*)&bcs[ph*16 + 12];
    float Bv[16], Cv[16];
    #pragma unroll
    for (int k = 0; k < 8; k++) { un2(ub[k], Bv[2*k], Bv[2*k+1]); un2(uc[k], Cv[2*k], Cv[2*k+1]); }
    float u = dtv * xv;
    float y = 0.f;
    #pragma unroll
    for (int s = 0; s < 16; s++) {
      float dA = __expf(dtv * A[s]);
      h[s] = dA * h[s] + u * Bv[s];
      y += h[s] * Cv[s];
    }
    float zv = b2f(xz[(size_t)row*ldxz + sIdx*xzDirOff + DI + d]);
    float yg = (y + xv * Dd) * (zv / (1.f + __expf(-zv)));
    yout[(size_t)row*DI + d] = f2b(yg);
  }
}

extern "C" void kernel_launch(void* const* d_in, const int* in_sizes, int n_in,
                              void* d_out, int out_size, void* d_ws, size_t ws_size,
                              hipStream_t stream)
{
  const float* x      = (const float*)d_in[0];
  const float* norm_g = (const float*)d_in[1];
  const float* norm_b = (const float*)d_in[2];
  const float* fi  = (const float*)d_in[3];
  const float* fcw = (const float*)d_in[4];
  const float* fcb = (const float*)d_in[5];
  const float* fxp = (const float*)d_in[6];
  const float* fdt = (const float*)d_in[7];
  const float* fdb = (const float*)d_in[8];
  const float* fa  = (const float*)d_in[9];
  const float* fD  = (const float*)d_in[10];
  const float* fo  = (const float*)d_in[11];
  const float* bi  = (const float*)d_in[12];
  const float* bcw = (const float*)d_in[13];
  const float* bcb = (const float*)d_in[14];
  const float* bxp = (const float*)d_in[15];
  const float* bdt = (const float*)d_in[16];
  const float* bdb = (const float*)d_in[17];
  const float* ba  = (const float*)d_in[18];
  const float* bD  = (const float*)d_in[19];
  const float* bo  = (const float*)d_in[20];
  const float* mix_w  = (const float*)d_in[21];
  const float* mix_b  = (const float*)d_in[22];
  const float* ffn_w1 = (const float*)d_in[23];
  const float* ffn_b1 = (const float*)d_in[24];
  const float* ffn_w2 = (const float*)d_in[25];
  const float* ffn_b2 = (const float*)d_in[26];
  const float* ffn_ng = (const float*)d_in[27];
  const float* ffn_nb = (const float*)d_in[28];

  auto al = [](size_t x){ return (x + 255) & ~(size_t)255; };
  // fixed-region element counts
  const size_t fixedB =
      al((size_t)2*SZ_AN*4) + al((size_t)2*SZ_DTW*2) + al((size_t)2*SZ_INW*2) +
      al((size_t)2*SZ_XP*2) + al((size_t)2*SZ_OUT*2) + al((size_t)SZ_MIX*2) +
      al((size_t)SZ_F1*2) + al((size_t)SZ_F1*2) + al((size_t)MM*DD*2) + al((size_t)MM*DI*2);
  const size_t concB = fixedB + al((size_t)MM*2*DI*2*2) + 2*al((size_t)2*MM*DI*2) +
      al((size_t)2*MM*96*2) + 3*al((size_t)2*NB*NCH*DI*16*4);
  const bool conc = (ws_size >= concB);

  size_t o = 0;
  char* wsb = (char*)d_ws;
  auto nxt = [&](size_t bytes) -> char* {
    char* p = wsb + o; o += (bytes + 255) & ~(size_t)255; return p;
  };
  float* An2   = (float*)nxt((size_t)2*SZ_AN*4);
  bf16*  dtwp2 = (bf16*) nxt((size_t)2*SZ_DTW*2);
  bf16*  w_in  = (bf16*) nxt((size_t)2*SZ_INW*2);
  bf16*  w_xp2 = (bf16*) nxt((size_t)2*SZ_XP*2);
  bf16*  w_out2= (bf16*) nxt((size_t)2*SZ_OUT*2);
  bf16*  w_mix = (bf16*) nxt((size_t)SZ_MIX*2);
  bf16*  w_f1  = (bf16*) nxt((size_t)SZ_F1*2);
  bf16*  w_f2  = (bf16*) nxt((size_t)SZ_F1*2);
  bf16*  xn    = (bf16*) nxt((size_t)MM*DD*2);        // reused as hn
  bf16*  xfb   = (bf16*) nxt((size_t)MM*DI*2);

  bf16 *xz, *xc, *dtb, *dbc;  float *Pp, *Sp, *h0, *hbuf;
  int ldxz, xzDirOff;
  size_t sXc, sDbc, sDt;
  if (conc) {
    xz  = (bf16*) nxt((size_t)MM*2*DI*2*2);           // [4096][6144], reused as a1
    xc  = (bf16*) nxt((size_t)2*MM*DI*2);             // [2][4096][1536], yout aliases
    dtb = (bf16*) nxt((size_t)2*MM*DI*2);
    dbc = (bf16*) nxt((size_t)2*MM*96*2);
    Pp  = (float*)nxt((size_t)2*NB*NCH*DI*16*4);
    Sp  = (float*)nxt((size_t)2*NB*NCH*DI*16*4);
    h0  = (float*)nxt((size_t)2*NB*NCH*DI*16*4);
    hbuf = Pp;                                        // 12.58 MB, dead scan scratch
    ldxz = 2*2*DI; xzDirOff = 2*DI;
    sXc = (size_t)MM*DI; sDbc = (size_t)MM*96; sDt = (size_t)MM*DI;
  } else {
    xz  = (bf16*) nxt((size_t)MM*2*DI*2);             // [4096][3072], reused as a1
    xc  = (bf16*) nxt((size_t)MM*DI*2);
    dtb = (bf16*) nxt((size_t)MM*DI*2);
    dbc = (bf16*) nxt((size_t)MM*96*2);
    Pp  = (float*)nxt((size_t)NB*NCH*DI*16*4);
    Sp  = (float*)nxt((size_t)NB*NCH*DI*16*4);
    h0  = (float*)nxt((size_t)NB*NCH*DI*16*4);
    hbuf = (float*)dtb;                               // 12.58 MB, dead after scans
    ldxz = 2*DI; xzDirOff = 0;
    sXc = 0; sDbc = 0; sDt = 0;
  }
  bf16* hn = xn;
  bf16* a1 = xz;

  const int prepN = 2*SZ_INW + 2*SZ_XP + 2*SZ_OUT + 2*SZ_DTW + 2*SZ_AN + SZ_MIX + 2*SZ_F1;
  prep_all_kernel<<<(prepN + 255)/256, 256, 0, stream>>>(
      fi, bi, fxp, bxp, fo, bo, fdt, bdt, fa, ba, mix_w, ffn_w1, ffn_w2,
      w_in, w_xp2, w_out2, dtwp2, An2, w_mix, w_f1, w_f2);

  ln_kernel<<<MM, 256, 0, stream>>>(x, norm_g, norm_b, xn);

  if (conc) {
    // in_proj both dirs: N=6144, 1536 blocks
    gemm_kernel<<<dim3(32, 48), 256, 0, stream>>>(xn, DD, w_in, DD, xz, ldxz,
                                                  2*2*DI, DD, nullptr, nullptr, 0,
                                                  ACT_NONE, 0);
    conv_silu_kernel<<<dim3(12, MM), 256, 0, stream>>>(xz, ldxz, xzDirOff,
                                                       fcw, fcb, bcw, bcb, xc, sXc, 0);
    gemm64_kernel<<<dim3(64, 2, 2), 256, 0, stream>>>(xc, DI, sXc, w_xp2, DI, (size_t)SZ_XP,
                                                      dbc, 96, sDbc, 80, DI,
                                                      nullptr, nullptr, 0, nullptr, 0, ACT_NONE, 0);
    gemm64_kernel<<<dim3(64, 24, 2), 256, 0, stream>>>(dbc, 96, sDbc, dtwp2, 64, (size_t)SZ_DTW,
                                                       dtb, DI, sDt, DI, 64,
                                                       fdb, bdb, 0, nullptr, 0, ACT_SOFTPLUS, 0);
    scan_partial<<<dim3(DI/256, NCH, 4), 256, 0, stream>>>(dtb, sDt, xc, sXc, dbc, sDbc,
                                                           An2, (size_t)SZ_AN, Pp, Sp, 0);
    scan_combine<<<dim3(DI*16/256, NB, 2), 256, 0, stream>>>(Pp, Sp, h0, 0);
    scan_final<<<dim3(DI/256, NCH, 4), 256, 0, stream>>>(dtb, sDt, xc, sXc, dbc, sDbc,
                                                         xz, ldxz, xzDirOff, An2, (size_t)SZ_AN,
                                                         fD, bD, h0, xc, sXc, 0);
    gemm64_kernel<<<dim3(64, 12, 2), 256, 0, stream>>>(xc, DI, sXc, w_out2, DI, (size_t)SZ_OUT,
                                                       xfb, 2*DD, (size_t)DD, DD, DI,
                                                       nullptr, nullptr, 0, nullptr, 0, ACT_NONE, 0);
  } else {
    for (int dir = 0; dir < 2; ++dir) {
      gemm_kernel<<<dim3(32, 24), 256, 0, stream>>>(xn, DD, w_in + (size_t)dir*SZ_INW, DD,
                                                    xz, ldxz, 2*DI, DD, nullptr, nullptr, 0,
                                                    ACT_NONE, 0);
      conv_silu_kernel<<<dim3(6, MM), 256, 0, stream>>>(xz, ldxz, 0,
                                                        fcw, fcb, bcw, bcb, xc, 0, dir);
      gemm64_kernel<<<dim3(64, 2, 1), 256, 0, stream>>>(xc, DI, 0, w_xp2 + (size_t)dir*SZ_XP, DI, 0,
                                                        dbc, 96, 0, 80, DI,
                                                        nullptr, nullptr, 0, nullptr, 0, ACT_NONE, 0);
      gemm64_kernel<<<dim3(64, 24, 1), 256, 0, stream>>>(dbc, 96, 0, dtwp2 + (size_t)dir*SZ_DTW, 64, 0,
                                                         dtb, DI, 0, DI, 64,
                                                         fdb, bdb, dir, nullptr, 0, ACT_SOFTPLUS, 0);
      scan_partial<<<dim3(DI/256, NCH, 2), 256, 0, stream>>>(dtb, 0, xc, 0, dbc, 0,
                                                             An2 + (size_t)dir*SZ_AN, 0, Pp, Sp, dir);
      scan_combine<<<dim3(DI*16/256, NB, 1), 256, 0, stream>>>(Pp, Sp, h0, dir);
      scan_final<<<dim3(DI/256, NCH, 2), 256, 0, stream>>>(dtb, 0, xc, 0, dbc, 0,
                                                           xz, ldxz, 0, An2 + (size_t)dir*SZ_AN, 0,
                                                           fD, bD, h0, xc, 0, dir);
      gemm64_kernel<<<dim3(64, 12, 1), 256, 0, stream>>>(xc, DI, 0, w_out2 + (size_t)dir*SZ_OUT, DI, 0,
                                                         (void*)((bf16*)xfb + dir*DD), 2*DD, 0, DD, DI,
                                                         nullptr, nullptr, 0, nullptr, 0, ACT_NONE, 0);
    }
  }

  // mix: xfb @ mix_w^T + mix_b + x -> hbuf (f32)
  gemm64_kernel<<<dim3(64, 12, 1), 256, 0, stream>>>(xfb, 2*DD, 0, w_mix, 2*DD, 0,
                                                     hbuf, DD, 0, DD, 2*DD,
                                                     mix_b, mix_b, 0, x, DD, ACT_NONE, 1);
  ln_kernel<<<MM, 256, 0, stream>>>(hbuf, ffn_ng, ffn_nb, hn);
  // ffn1: gelu(hn @ w1^T + b1) -> a1
  gemm_kernel<<<dim3(32, 24), 256, 0, stream>>>(hn, DD, w_f1, DD, a1, 4*DD,
                                                4*DD, DD, ffn_b1, nullptr, 0, ACT_GELU, 0);
  // ffn2: a1 @ w2^T + b2 + hbuf -> d_out (f32)
  gemm64_kernel<<<dim3(64, 12, 1), 256, 0, stream>>>(a1, 4*DD, 0, w_f2, 4*DD, 0,
                                                     d_out, DD, 0, DD, 4*DD,
                                                     ffn_b2, ffn_b2, 0, hbuf, DD, ACT_NONE, 1);
}

// Round 8
// 617.936 us; speedup vs baseline: 1.2277x; 1.2277x over previous
//
#include <hip/hip_runtime.h>
#include <hip/hip_bf16.h>
#include <math.h>

#define NB 2
#define LL 2048
#define DD 768
#define DI 1536
#define DS 16
#define MM (NB*LL)   // 4096
#define TCH 64       // scan chunk length
#define NCH 32       // 2048 / TCH

typedef __hip_bfloat16 bf16;
typedef __attribute__((ext_vector_type(8))) __bf16 bf16x8;
typedef __attribute__((ext_vector_type(4))) float f32x4;

__device__ __forceinline__ float b2f(bf16 v){ return __bfloat162float(v); }
__device__ __forceinline__ bf16 f2b(float v){ return __float2bfloat16(v); }

__device__ __forceinline__ void un2(unsigned u, float& lo, float& hi){
  union {unsigned i; float f;} a, b;
  a.i = u << 16; b.i = u & 0xffff0000u;
  lo = a.f; hi = b.f;
}

__device__ __forceinline__ void async_cp16(const bf16* g, __bf16* l) {
  __builtin_amdgcn_global_load_lds((const __attribute__((address_space(1))) void*)g,
                                   (__attribute__((address_space(3))) void*)l, 16, 0, 0);
}

#define ACT_NONE 0
#define ACT_SOFTPLUS 1
#define ACT_GELU 2

__device__ __forceinline__ float apply_act(float v, int act) {
  if (act == ACT_SOFTPLUS) {
    v = (v > 15.f) ? v : log1pf(__expf(v));
  } else if (act == ACT_GELU) {
    float u = 0.7978845608028654f * (v + 0.044715f*v*v*v);
    v = 0.5f * v * (1.f + tanhf(u));
  }
  return v;
}

// ---------------- 128x128 tile, BK=64, XOR-swizzled LDS ----------------
__global__ void gemm_kernel(const bf16* __restrict__ A, int lda,
                            const bf16* __restrict__ B, int ldb,
                            void* __restrict__ C, int ldc,
                            int N, int K,
                            const float* __restrict__ bias,
                            const float* __restrict__ addp, int ldadd,
                            int act, int f32out)
{
  __shared__ __bf16 As[128*64];   // 16 KB
  __shared__ __bf16 Bs[128*64];   // 16 KB
  const int tid  = threadIdx.x;
  const int lane = tid & 63, wave = tid >> 6;
  const int m0 = blockIdx.x * 128, n0 = blockIdx.y * 128;
  const int wm = wave & 1, wn = wave >> 1;

  const int srow = wave*32 + (lane >> 3);
  const int gsw  = (lane & 7) ^ ((lane >> 3) & 7);
  const int scol = gsw * 8;
  const bf16* Ag[4]; const bf16* Bg[4];
  __bf16 *AsW[4], *BsW[4];
  #pragma unroll
  for (int i = 0; i < 4; i++) {
    int ar = m0 + srow + i*8;
    Ag[i] = A + (size_t)ar * lda + scol;
    int br = n0 + srow + i*8; if (br > N-1) br = N-1;
    Bg[i] = B + (size_t)br * ldb + scol;
    AsW[i] = &As[(wave*32 + i*8)*64];
    BsW[i] = &Bs[(wave*32 + i*8)*64];
  }

  f32x4 acc[4][4] = {};
  const int arow = wm*64 + (lane & 15);
  const int brow = wn*64 + (lane & 15);
  const int rx = lane & 7;
  const int gq = lane >> 4;

  for (int kb = 0; kb < K; kb += 64) {
    __syncthreads();
    #pragma unroll
    for (int i = 0; i < 4; i++) {
      async_cp16(Ag[i] + kb, AsW[i]);
      async_cp16(Bg[i] + kb, BsW[i]);
    }
    __syncthreads();
    #pragma unroll
    for (int h = 0; h < 2; h++) {
      const int kk = ((h*4 + gq) ^ rx) * 8;
      bf16x8 af[4], bfr[4];
      #pragma unroll
      for (int i = 0; i < 4; i++) af[i]  = *(const bf16x8*)&As[(arow + i*16)*64 + kk];
      #pragma unroll
      for (int j = 0; j < 4; j++) bfr[j] = *(const bf16x8*)&Bs[(brow + j*16)*64 + kk];
      #pragma unroll
      for (int i = 0; i < 4; i++)
        #pragma unroll
        for (int j = 0; j < 4; j++)
          acc[i][j] = __builtin_amdgcn_mfma_f32_16x16x32_bf16(af[i], bfr[j], acc[i][j], 0, 0, 0);
    }
  }

  bf16*  Cb = (bf16*)C;
  float* Cf = (float*)C;
  #pragma unroll
  for (int i = 0; i < 4; i++) {
    int rbase = m0 + wm*64 + i*16 + (lane >> 4)*4;
    #pragma unroll
    for (int j = 0; j < 4; j++) {
      int col = n0 + wn*64 + j*16 + (lane & 15);
      if (col >= N) continue;
      float bv = bias ? bias[col] : 0.f;
      #pragma unroll
      for (int r = 0; r < 4; r++) {
        int row = rbase + r;
        float v = apply_act(acc[i][j][r] + bv, act);
        if (addp) v += addp[(size_t)row * ldadd + col];
        if (f32out) Cf[(size_t)row * ldc + col] = v;
        else        Cb[(size_t)row * ldc + col] = f2b(v);
      }
    }
  }
}

// ---------------- 64x64 tile, BK=64, swizzled, z-strided ----------------
__global__ void gemm64_kernel(const bf16* __restrict__ A, int lda, size_t sA,
                              const bf16* __restrict__ B, int ldb, size_t sB,
                              void* __restrict__ C, int ldc, size_t sC,
                              int N, int K,
                              const float* __restrict__ bias0,
                              const float* __restrict__ bias1, int biasBase,
                              const float* __restrict__ addp, int ldadd,
                              int act, int f32out)
{
  __shared__ __bf16 As[64*64];    // 8 KB
  __shared__ __bf16 Bs[64*64];    // 8 KB
  const int tid  = threadIdx.x;
  const int lane = tid & 63, wave = tid >> 6;
  const int z = blockIdx.z;
  A += (size_t)z * sA;
  B += (size_t)z * sB;
  const float* bias = ((biasBase + z) ? bias1 : bias0);
  const int m0 = blockIdx.x * 64, n0 = blockIdx.y * 64;
  const int wm = wave & 1, wn = wave >> 1;

  const int srow = wave*16 + (lane >> 3);
  const int gsw  = (lane & 7) ^ ((lane >> 3) & 7);
  const int scol = gsw * 8;
  const bf16* Ag[2]; const bf16* Bg[2];
  __bf16 *AsW[2], *BsW[2];
  #pragma unroll
  for (int i = 0; i < 2; i++) {
    int ar = m0 + srow + i*8;
    Ag[i] = A + (size_t)ar * lda + scol;
    int br = n0 + srow + i*8; if (br > N-1) br = N-1;
    Bg[i] = B + (size_t)br * ldb + scol;
    AsW[i] = &As[(wave*16 + i*8)*64];
    BsW[i] = &Bs[(wave*16 + i*8)*64];
  }

  f32x4 acc[2][2] = {};
  const int arow = wm*32 + (lane & 15);
  const int brow = wn*32 + (lane & 15);
  const int rx = lane & 7;
  const int gq = lane >> 4;

  for (int kb = 0; kb < K; kb += 64) {
    __syncthreads();
    #pragma unroll
    for (int i = 0; i < 2; i++) {
      async_cp16(Ag[i] + kb, AsW[i]);
      async_cp16(Bg[i] + kb, BsW[i]);
    }
    __syncthreads();
    #pragma unroll
    for (int h = 0; h < 2; h++) {
      const int kk = ((h*4 + gq) ^ rx) * 8;
      bf16x8 af[2], bfr[2];
      #pragma unroll
      for (int i = 0; i < 2; i++) af[i]  = *(const bf16x8*)&As[(arow + i*16)*64 + kk];
      #pragma unroll
      for (int j = 0; j < 2; j++) bfr[j] = *(const bf16x8*)&Bs[(brow + j*16)*64 + kk];
      #pragma unroll
      for (int i = 0; i < 2; i++)
        #pragma unroll
        for (int j = 0; j < 2; j++)
          acc[i][j] = __builtin_amdgcn_mfma_f32_16x16x32_bf16(af[i], bfr[j], acc[i][j], 0, 0, 0);
    }
  }

  bf16*  Cb = (bf16*)C + z*sC;
  float* Cf = (float*)C + z*sC;
  #pragma unroll
  for (int i = 0; i < 2; i++) {
    int rbase = m0 + wm*32 + i*16 + (lane >> 4)*4;
    #pragma unroll
    for (int j = 0; j < 2; j++) {
      int col = n0 + wn*32 + j*16 + (lane & 15);
      if (col >= N) continue;
      float bv = bias ? bias[col] : 0.f;
      #pragma unroll
      for (int r = 0; r < 4; r++) {
        int row = rbase + r;
        float v = apply_act(acc[i][j][r] + bv, act);
        if (addp) v += addp[(size_t)row * ldadd + col];
        if (f32out) Cf[(size_t)row * ldc + col] = v;
        else        Cb[(size_t)row * ldc + col] = f2b(v);
      }
    }
  }
}

// ---------------- LayerNorm over D=768; fp32 in, bf16 out ----------------
__global__ void ln_kernel(const float* __restrict__ x, const float* __restrict__ g,
                          const float* __restrict__ b, bf16* __restrict__ out)
{
  const int row = blockIdx.x;
  const int tid = threadIdx.x;
  const float* xr = x + (size_t)row * DD;
  float v[3], s = 0.f, s2 = 0.f;
  #pragma unroll
  for (int i = 0; i < 3; i++) {
    float f = xr[tid + i*256];
    v[i] = f; s += f; s2 += f*f;
  }
  #pragma unroll
  for (int o = 32; o > 0; o >>= 1) { s += __shfl_down(s, o, 64); s2 += __shfl_down(s2, o, 64); }
  __shared__ float ps[4], ps2[4];
  int wave = tid >> 6;
  if ((tid & 63) == 0) { ps[wave] = s; ps2[wave] = s2; }
  __syncthreads();
  s = ps[0]+ps[1]+ps[2]+ps[3]; s2 = ps2[0]+ps2[1]+ps2[2]+ps2[3];
  float mu = s * (1.f/DD);
  float var = s2 * (1.f/DD) - mu*mu;
  float rs = rsqrtf(var + 1e-5f);
  #pragma unroll
  for (int i = 0; i < 3; i++) {
    int c = tid + i*256;
    float o = (v[i] - mu) * rs * g[c] + b[c];
    out[(size_t)row * DD + c] = f2b(o);
  }
}

// ---------------- conv(K=4) + silu; dir0 causal, dir1 anti-causal --------
__global__ void conv_silu_kernel(const bf16* __restrict__ xz, int ldxz, int xzDirOff,
                                 const float* __restrict__ cw0, const float* __restrict__ cb0,
                                 const float* __restrict__ cw1, const float* __restrict__ cb1,
                                 bf16* __restrict__ xc, size_t sXc, int dirBase)
{
  int idx = blockIdx.x * 256 + threadIdx.x;
  int sIdx = (idx >= DI) ? 1 : 0;
  int d = idx - sIdx*DI;
  int dir = dirBase + sIdx;
  int row = blockIdx.y;
  int b = row >> 11, t = row & 2047;
  const float* cw = dir ? cw1 : cw0;
  const float* cb = dir ? cb1 : cb0;
  float acc = cb[d];
  float w0 = cw[d*4+0], w1 = cw[d*4+1], w2 = cw[d*4+2], w3 = cw[d*4+3];
  const bf16* base = xz + (size_t)(b*2048) * ldxz + sIdx*xzDirOff + d;
  if (dir == 0) {
    if (t >= 3) acc += b2f(base[(size_t)(t-3)*ldxz]) * w0;
    if (t >= 2) acc += b2f(base[(size_t)(t-2)*ldxz]) * w1;
    if (t >= 1) acc += b2f(base[(size_t)(t-1)*ldxz]) * w2;
    acc += b2f(base[(size_t)t*ldxz]) * w3;
  } else {
    if (t <= 2044) acc += b2f(base[(size_t)(t+3)*ldxz]) * w0;
    if (t <= 2045) acc += b2f(base[(size_t)(t+2)*ldxz]) * w1;
    if (t <= 2046) acc += b2f(base[(size_t)(t+1)*ldxz]) * w2;
    acc += b2f(base[(size_t)t*ldxz]) * w3;
  }
  float y = acc / (1.f + __expf(-acc));
  xc[sIdx*sXc + (size_t)row * DI + d] = f2b(y);
}

// ---------------- one-shot weight prep ----------------
#define SZ_INW (2*DI*DD)
#define SZ_XP  (80*DI)
#define SZ_OUT (DD*DI)
#define SZ_DTW (DI*64)
#define SZ_AN  (DI*16)
#define SZ_MIX (2*DD*DD)
#define SZ_F1  (4*DD*DD)
__global__ void prep_all_kernel(const float* fi, const float* bi,
                                const float* fxp, const float* bxp,
                                const float* fo, const float* bo,
                                const float* fdt, const float* bdt,
                                const float* fa, const float* ba,
                                const float* mw, const float* f1, const float* f2,
                                bf16* w_in, bf16* w_xp2, bf16* w_out2, bf16* dtwp2,
                                float* An2, bf16* w_mix, bf16* w_f1, bf16* w_f2)
{
  int i = blockIdx.x * 256 + threadIdx.x;
  if (i < SZ_INW) { w_in[i] = f2b(fi[i]); return; }               i -= SZ_INW;
  if (i < SZ_INW) { w_in[SZ_INW + i] = f2b(bi[i]); return; }      i -= SZ_INW;
  if (i < SZ_XP)  { w_xp2[i] = f2b(fxp[i]); return; }             i -= SZ_XP;
  if (i < SZ_XP)  { w_xp2[SZ_XP + i] = f2b(bxp[i]); return; }     i -= SZ_XP;
  if (i < SZ_OUT) { w_out2[i] = f2b(fo[i]); return; }             i -= SZ_OUT;
  if (i < SZ_OUT) { w_out2[SZ_OUT + i] = f2b(bo[i]); return; }    i -= SZ_OUT;
  if (i < SZ_DTW) { int r=i>>6,c=i&63; dtwp2[i] = (c<48)?f2b(fdt[r*48+c]):f2b(0.f); return; } i -= SZ_DTW;
  if (i < SZ_DTW) { int r=i>>6,c=i&63; dtwp2[SZ_DTW+i] = (c<48)?f2b(bdt[r*48+c]):f2b(0.f); return; } i -= SZ_DTW;
  if (i < SZ_AN)  { int d=i>>4,s=i&15; An2[s*DI+d] = -__expf(fa[i]); return; } i -= SZ_AN;
  if (i < SZ_AN)  { int d=i>>4,s=i&15; An2[SZ_AN + s*DI+d] = -__expf(ba[i]); return; } i -= SZ_AN;
  if (i < SZ_MIX) { w_mix[i] = f2b(mw[i]); return; }              i -= SZ_MIX;
  if (i < SZ_F1)  { w_f1[i] = f2b(f1[i]); return; }               i -= SZ_F1;
  w_f2[i] = f2b(f2[i]);
}

// ---------------- chunked parallel scan (dir-aware, prefetched) ----------------
// z decodes (sIdx, b): sIdx = z>>1, b = z&1; dir = dirBase + sIdx.
__global__ void scan_partial(const bf16* __restrict__ dt, size_t sDt,
                             const bf16* __restrict__ xc, size_t sXc,
                             const bf16* __restrict__ dbc, size_t sDbc,
                             const float* __restrict__ An, size_t sAn,
                             float* __restrict__ Pp, float* __restrict__ Sp,
                             int dirBase)
{
  const int tid = threadIdx.x;
  const int sIdx = blockIdx.z >> 1, b = blockIdx.z & 1;
  const int dir = dirBase + sIdx;
  const int c = blockIdx.y;
  const int d = blockIdx.x * 256 + tid;
  dt  += sIdx*sDt; xc += sIdx*sXc; dbc += sIdx*sDbc;
  const int rowbase = b*2048 + c*TCH;
  __shared__ unsigned bcs[TCH*16];
  for (int i = tid; i < TCH*16; i += 256) {
    int r = i >> 4, dw = i & 15;
    bcs[i] = ((const unsigned*)(dbc + (size_t)(rowbase + r)*96 + 48))[dw];
  }
  __syncthreads();
  float A[16], P[16], g[16];
  #pragma unroll
  for (int s = 0; s < 16; s++) { A[s] = An[sIdx*sAn + s*DI + d]; P[s] = 1.f; g[s] = 0.f; }
  int ph0 = dir ? (TCH-1) : 0;
  float dtv = b2f(dt[(size_t)(rowbase+ph0)*DI + d]);
  float xv  = b2f(xc[(size_t)(rowbase+ph0)*DI + d]);
  for (int t = 0; t < TCH; t++) {
    const int ph = dir ? (TCH-1-t) : t;
    const int tn = (t+1 < TCH) ? t+1 : t;
    const int phn = dir ? (TCH-1-tn) : tn;
    float dtn = b2f(dt[(size_t)(rowbase+phn)*DI + d]);
    float xvn = b2f(xc[(size_t)(rowbase+phn)*DI + d]);
    unsigned ub[8];
    *(uint4*)&ub[0] = *(const uint4*)&bcs[ph*16];
    *(uint4*)&ub[4] = *(const uint4*)&bcs[ph*16 + 4];
    float Bv[16];
    #pragma unroll
    for (int k = 0; k < 8; k++) un2(ub[k], Bv[2*k], Bv[2*k+1]);
    float u = dtv * xv;
    #pragma unroll
    for (int s = 0; s < 16; s++) {
      float dA = __expf(dtv * A[s]);
      P[s] *= dA;
      g[s] = dA * g[s] + u * Bv[s];
    }
    dtv = dtn; xv = xvn;
  }
  size_t base = ((((size_t)sIdx*NB + b)*NCH + c)*DI + d) * 16;
  #pragma unroll
  for (int s = 0; s < 16; s++) { Pp[base+s] = P[s]; Sp[base+s] = g[s]; }
}

__global__ void scan_combine(const float* __restrict__ Pp, const float* __restrict__ Sp,
                             float* __restrict__ h0, int dirBase)
{
  const int j = blockIdx.x * 256 + threadIdx.x;
  const int b = blockIdx.y;
  const int sIdx = blockIdx.z;
  const int dir = dirBase + sIdx;
  float h = 0.f;
  for (int k = 0; k < NCH; k++) {
    int c = dir ? (NCH-1-k) : k;
    size_t idx = (((size_t)sIdx*NB + b)*NCH + c)*DI*16 + j;
    h0[idx] = h;
    h = Pp[idx]*h + Sp[idx];
  }
}

__global__ void scan_final(const bf16* __restrict__ dt, size_t sDt,
                           const bf16* __restrict__ xc, size_t sXc,
                           const bf16* __restrict__ dbc, size_t sDbc,
                           const bf16* __restrict__ xz, int ldxz, int xzDirOff,
                           const float* __restrict__ An, size_t sAn,
                           const float* __restrict__ Dp0, const float* __restrict__ Dp1,
                           const float* __restrict__ h0,
                           bf16* __restrict__ yout, size_t sY, int dirBase)
{
  const int tid = threadIdx.x;
  const int sIdx = blockIdx.z >> 1, b = blockIdx.z & 1;
  const int dir = dirBase + sIdx;
  const int c = blockIdx.y;
  const int d = blockIdx.x * 256 + tid;
  dt += sIdx*sDt; xc += sIdx*sXc; dbc += sIdx*sDbc; yout += sIdx*sY;
  const float* Dp = dir ? Dp1 : Dp0;
  const int rowbase = b*2048 + c*TCH;
  __shared__ unsigned bcs[TCH*16];
  for (int i = tid; i < TCH*16; i += 256) {
    int r = i >> 4, dw = i & 15;
    bcs[i] = ((const unsigned*)(dbc + (size_t)(rowbase + r)*96 + 48))[dw];
  }
  __syncthreads();
  float A[16], h[16];
  size_t hbase = ((((size_t)sIdx*NB + b)*NCH + c)*DI + d) * 16;
  #pragma unroll
  for (int s = 0; s < 16; s++) { A[s] = An[sIdx*sAn + s*DI + d]; h[s] = h0[hbase+s]; }
  const float Dd = Dp[d];
  const bf16* zp = xz + sIdx*xzDirOff + DI + d;
  int ph0 = dir ? (TCH-1) : 0;
  float dtv = b2f(dt[(size_t)(rowbase+ph0)*DI + d]);
  float xv  = b2f(xc[(size_t)(rowbase+ph0)*DI + d]);
  float zv  = b2f(zp[(size_t)(rowbase+ph0)*ldxz]);
  for (int t = 0; t < TCH; t++) {
    const int ph = dir ? (TCH-1-t) : t;
    const int row = rowbase + ph;
    const int tn = (t+1 < TCH) ? t+1 : t;
    const int phn = dir ? (TCH-1-tn) : tn;
    float dtn = b2f(dt[(size_t)(rowbase+phn)*DI + d]);
    float xvn = b2f(xc[(size_t)(rowbase+phn)*DI + d]);
    float zvn = b2f(zp[(size_t)(rowbase+phn)*ldxz]);
    unsigned ub[8], uc[8];
    *(uint4*)&ub[0] = *(const uint4*)&bcs[ph*16];
    *(uint4*)&ub[4] = *(const uint4*)&bcs[ph*16 + 4];
    *(uint4*)&uc[0] = *(const uint4*)&bcs[ph*16 + 8];
    *(uint4*)&uc[4] = *(const uint4*)&bcs[ph*16 + 12];
    float Bv[16], Cv[16];
    #pragma unroll
    for (int k = 0; k < 8; k++) { un2(ub[k], Bv[2*k], Bv[2*k+1]); un2(uc[k], Cv[2*k], Cv[2*k+1]); }
    float u = dtv * xv;
    float y = 0.f;
    #pragma unroll
    for (int s = 0; s < 16; s++) {
      float dA = __expf(dtv * A[s]);
      h[s] = dA * h[s] + u * Bv[s];
      y += h[s] * Cv[s];
    }
    float yg = (y + xv * Dd) * (zv / (1.f + __expf(-zv)));
    yout[(size_t)row*DI + d] = f2b(yg);
    dtv = dtn; xv = xvn; zv = zvn;
  }
}

extern "C" void kernel_launch(void* const* d_in, const int* in_sizes, int n_in,
                              void* d_out, int out_size, void* d_ws, size_t ws_size,
                              hipStream_t stream)
{
  const float* x      = (const float*)d_in[0];
  const float* norm_g = (const float*)d_in[1];
  const float* norm_b = (const float*)d_in[2];
  const float* fi  = (const float*)d_in[3];
  const float* fcw = (const float*)d_in[4];
  const float* fcb = (const float*)d_in[5];
  const float* fxp = (const float*)d_in[6];
  const float* fdt = (const float*)d_in[7];
  const float* fdb = (const float*)d_in[8];
  const float* fa  = (const float*)d_in[9];
  const float* fD  = (const float*)d_in[10];
  const float* fo  = (const float*)d_in[11];
  const float* bi  = (const float*)d_in[12];
  const float* bcw = (const float*)d_in[13];
  const float* bcb = (const float*)d_in[14];
  const float* bxp = (const float*)d_in[15];
  const float* bdt = (const float*)d_in[16];
  const float* bdb = (const float*)d_in[17];
  const float* ba  = (const float*)d_in[18];
  const float* bD  = (const float*)d_in[19];
  const float* bo  = (const float*)d_in[20];
  const float* mix_w  = (const float*)d_in[21];
  const float* mix_b  = (const float*)d_in[22];
  const float* ffn_w1 = (const float*)d_in[23];
  const float* ffn_b1 = (const float*)d_in[24];
  const float* ffn_w2 = (const float*)d_in[25];
  const float* ffn_b2 = (const float*)d_in[26];
  const float* ffn_ng = (const float*)d_in[27];
  const float* ffn_nb = (const float*)d_in[28];

  auto al = [](size_t x){ return (x + 255) & ~(size_t)255; };
  const size_t fixedB =
      al((size_t)2*SZ_AN*4) + al((size_t)2*SZ_DTW*2) + al((size_t)2*SZ_INW*2) +
      al((size_t)2*SZ_XP*2) + al((size_t)2*SZ_OUT*2) + al((size_t)SZ_MIX*2) +
      al((size_t)SZ_F1*2) + al((size_t)SZ_F1*2) + al((size_t)MM*DD*2) + al((size_t)MM*DI*2);
  const size_t concB = fixedB + al((size_t)MM*2*DI*2*2) + 2*al((size_t)2*MM*DI*2) +
      al((size_t)2*MM*96*2) + 3*al((size_t)2*NB*NCH*DI*16*4);
  const bool conc = (ws_size >= concB);

  size_t o = 0;
  char* wsb = (char*)d_ws;
  auto nxt = [&](size_t bytes) -> char* {
    char* p = wsb + o; o += (bytes + 255) & ~(size_t)255; return p;
  };
  float* An2   = (float*)nxt((size_t)2*SZ_AN*4);
  bf16*  dtwp2 = (bf16*) nxt((size_t)2*SZ_DTW*2);
  bf16*  w_in  = (bf16*) nxt((size_t)2*SZ_INW*2);
  bf16*  w_xp2 = (bf16*) nxt((size_t)2*SZ_XP*2);
  bf16*  w_out2= (bf16*) nxt((size_t)2*SZ_OUT*2);
  bf16*  w_mix = (bf16*) nxt((size_t)SZ_MIX*2);
  bf16*  w_f1  = (bf16*) nxt((size_t)SZ_F1*2);
  bf16*  w_f2  = (bf16*) nxt((size_t)SZ_F1*2);
  bf16*  xn    = (bf16*) nxt((size_t)MM*DD*2);        // reused as hn
  bf16*  xfb   = (bf16*) nxt((size_t)MM*DI*2);

  bf16 *xz, *xc, *dtb, *dbc;  float *Pp, *Sp, *h0, *hbuf;
  int ldxz, xzDirOff;
  size_t sXc, sDbc, sDt;
  if (conc) {
    xz  = (bf16*) nxt((size_t)MM*2*DI*2*2);           // [4096][6144], reused as a1
    xc  = (bf16*) nxt((size_t)2*MM*DI*2);
    dtb = (bf16*) nxt((size_t)2*MM*DI*2);
    dbc = (bf16*) nxt((size_t)2*MM*96*2);
    Pp  = (float*)nxt((size_t)2*NB*NCH*DI*16*4);
    Sp  = (float*)nxt((size_t)2*NB*NCH*DI*16*4);
    h0  = (float*)nxt((size_t)2*NB*NCH*DI*16*4);
    hbuf = Pp;
    ldxz = 2*2*DI; xzDirOff = 2*DI;
    sXc = (size_t)MM*DI; sDbc = (size_t)MM*96; sDt = (size_t)MM*DI;
  } else {
    xz  = (bf16*) nxt((size_t)MM*2*DI*2);
    xc  = (bf16*) nxt((size_t)MM*DI*2);
    dtb = (bf16*) nxt((size_t)MM*DI*2);
    dbc = (bf16*) nxt((size_t)MM*96*2);
    Pp  = (float*)nxt((size_t)NB*NCH*DI*16*4);
    Sp  = (float*)nxt((size_t)NB*NCH*DI*16*4);
    h0  = (float*)nxt((size_t)NB*NCH*DI*16*4);
    hbuf = (float*)dtb;
    ldxz = 2*DI; xzDirOff = 0;
    sXc = 0; sDbc = 0; sDt = 0;
  }
  bf16* hn = xn;
  bf16* a1 = xz;

  const int prepN = 2*SZ_INW + 2*SZ_XP + 2*SZ_OUT + 2*SZ_DTW + 2*SZ_AN + SZ_MIX + 2*SZ_F1;
  prep_all_kernel<<<(prepN + 255)/256, 256, 0, stream>>>(
      fi, bi, fxp, bxp, fo, bo, fdt, bdt, fa, ba, mix_w, ffn_w1, ffn_w2,
      w_in, w_xp2, w_out2, dtwp2, An2, w_mix, w_f1, w_f2);

  ln_kernel<<<MM, 256, 0, stream>>>(x, norm_g, norm_b, xn);

  if (conc) {
    gemm_kernel<<<dim3(32, 48), 256, 0, stream>>>(xn, DD, w_in, DD, xz, ldxz,
                                                  2*2*DI, DD, nullptr, nullptr, 0,
                                                  ACT_NONE, 0);
    conv_silu_kernel<<<dim3(12, MM), 256, 0, stream>>>(xz, ldxz, xzDirOff,
                                                       fcw, fcb, bcw, bcb, xc, sXc, 0);
    gemm64_kernel<<<dim3(64, 2, 2), 256, 0, stream>>>(xc, DI, sXc, w_xp2, DI, (size_t)SZ_XP,
                                                      dbc, 96, sDbc, 80, DI,
                                                      nullptr, nullptr, 0, nullptr, 0, ACT_NONE, 0);
    gemm64_kernel<<<dim3(64, 24, 2), 256, 0, stream>>>(dbc, 96, sDbc, dtwp2, 64, (size_t)SZ_DTW,
                                                       dtb, DI, sDt, DI, 64,
                                                       fdb, bdb, 0, nullptr, 0, ACT_SOFTPLUS, 0);
    scan_partial<<<dim3(DI/256, NCH, 4), 256, 0, stream>>>(dtb, sDt, xc, sXc, dbc, sDbc,
                                                           An2, (size_t)SZ_AN, Pp, Sp, 0);
    scan_combine<<<dim3(DI*16/256, NB, 2), 256, 0, stream>>>(Pp, Sp, h0, 0);
    scan_final<<<dim3(DI/256, NCH, 4), 256, 0, stream>>>(dtb, sDt, xc, sXc, dbc, sDbc,
                                                         xz, ldxz, xzDirOff, An2, (size_t)SZ_AN,
                                                         fD, bD, h0, xc, sXc, 0);
    gemm64_kernel<<<dim3(64, 12, 2), 256, 0, stream>>>(xc, DI, sXc, w_out2, DI, (size_t)SZ_OUT,
                                                       xfb, 2*DD, (size_t)DD, DD, DI,
                                                       nullptr, nullptr, 0, nullptr, 0, ACT_NONE, 0);
  } else {
    for (int dir = 0; dir < 2; ++dir) {
      gemm_kernel<<<dim3(32, 24), 256, 0, stream>>>(xn, DD, w_in + (size_t)dir*SZ_INW, DD,
                                                    xz, ldxz, 2*DI, DD, nullptr, nullptr, 0,
                                                    ACT_NONE, 0);
      conv_silu_kernel<<<dim3(6, MM), 256, 0, stream>>>(xz, ldxz, 0,
                                                        fcw, fcb, bcw, bcb, xc, 0, dir);
      gemm64_kernel<<<dim3(64, 2, 1), 256, 0, stream>>>(xc, DI, 0, w_xp2 + (size_t)dir*SZ_XP, DI, 0,
                                                        dbc, 96, 0, 80, DI,
                                                        nullptr, nullptr, 0, nullptr, 0, ACT_NONE, 0);
      gemm64_kernel<<<dim3(64, 24, 1), 256, 0, stream>>>(dbc, 96, 0, dtwp2 + (size_t)dir*SZ_DTW, 64, 0,
                                                         dtb, DI, 0, DI, 64,
                                                         fdb, bdb, dir, nullptr, 0, ACT_SOFTPLUS, 0);
      scan_partial<<<dim3(DI/256, NCH, 2), 256, 0, stream>>>(dtb, 0, xc, 0, dbc, 0,
                                                             An2 + (size_t)dir*SZ_AN, 0, Pp, Sp, dir);
      scan_combine<<<dim3(DI*16/256, NB, 1), 256, 0, stream>>>(Pp, Sp, h0, dir);
      scan_final<<<dim3(DI/256, NCH, 2), 256, 0, stream>>>(dtb, 0, xc, 0, dbc, 0,
                                                           xz, ldxz, 0, An2 + (size_t)dir*SZ_AN, 0,
                                                           fD, bD, h0, xc, 0, dir);
      gemm64_kernel<<<dim3(64, 12, 1), 256, 0, stream>>>(xc, DI, 0, w_out2 + (size_t)dir*SZ_OUT, DI, 0,
                                                         (void*)((bf16*)xfb + dir*DD), 2*DD, 0, DD, DI,
                                                         nullptr, nullptr, 0, nullptr, 0, ACT_NONE, 0);
    }
  }

  gemm64_kernel<<<dim3(64, 12, 1), 256, 0, stream>>>(xfb, 2*DD, 0, w_mix, 2*DD, 0,
                                                     hbuf, DD, 0, DD, 2*DD,
                                                     mix_b, mix_b, 0, x, DD, ACT_NONE, 1);
  ln_kernel<<<MM, 256, 0, stream>>>(hbuf, ffn_ng, ffn_nb, hn);
  gemm_kernel<<<dim3(32, 24), 256, 0, stream>>>(hn, DD, w_f1, DD, a1, 4*DD,
                                                4*DD, DD, ffn_b1, nullptr, 0, ACT_GELU, 0);
  gemm64_kernel<<<dim3(64, 12, 1), 256, 0, stream>>>(a1, 4*DD, 0, w_f2, 4*DD, 0,
                                                     d_out, DD, 0, DD, 4*DD,
                                                     ffn_b2, ffn_b2, 0, hbuf, DD, ACT_NONE, 1);
}